// Round 2
// baseline (42.995 us; speedup 1.0000x reference)
//
#include <hip/hip_runtime.h>
#include <hip/hip_bf16.h>

typedef __attribute__((ext_vector_type(8))) short s16x8;
typedef __attribute__((ext_vector_type(4))) float f32x4;
typedef __attribute__((ext_vector_type(4))) unsigned short u16x4;
typedef __attribute__((ext_vector_type(4))) float fl4;

__device__ __forceinline__ unsigned short f2bf(float f) {
  union { __hip_bfloat16 b; unsigned short u; } cv;
  cv.b = __float2bfloat16(f);
  return cv.u;
}

__device__ __forceinline__ void gl_lds16(const void* g, void* l) {
  __builtin_amdgcn_global_load_lds(
      (const __attribute__((address_space(1))) unsigned int*)g,
      (__attribute__((address_space(3))) unsigned int*)l, 16, 0, 0);
}

// ---------------- prepass: fp32 -> bf16 tile images in ws ----------------
// ws layout (shorts): Kb at 0, Qb at 2M, Vb at 4M; each 32bh x 16tiles x 4096.
// K/Q tile image: rows y=0..63, 128B/row, 16B chunk j at byte y*128 + ((j*16) ^ ((y&7)<<4)).
// V tile image (PV-permuted): short idx (((kp*4+g)*64+c)*8 + 4*tu + j) = V[32kp+16tu+4g+j][c] / 2048.
__global__ __launch_bounds__(256)
void prep_all(const float* __restrict__ tq, const float* __restrict__ tk,
              const float* __restrict__ tv, unsigned short* __restrict__ ws)
{
  const int bid  = (int)blockIdx.x;
  const int role = bid >> 9;           // 0=K, 1=Q, 2=V
  const int blk  = bid & 511;          // bh*16 + t
  const int bh = blk >> 4, t = blk & 15;
  const int b = bh >> 2, h = bh & 3;
  const int tid = (int)threadIdx.x;
  unsigned short* dst = ws + (size_t)role * 2097152 + (size_t)blk * 4096;

  if (role < 2) {
    const int sy = tid >> 2, sq4 = tid & 3;
    const float* src = (role ? tq : tk) + ((size_t)(b*1024 + t*64 + sy))*256 + h*64;
    const float scale = role ? 0.125f : 1.0f;
    char* row = (char*)dst + sy*128;
    const int ssw = (sy & 7) << 4;
#pragma unroll
    for (int j2 = 0; j2 < 4; ++j2) {
      fl4 v = *(const fl4*)(src + (sq4 + 4*j2)*4);
      u16x4 p;
      p[0] = f2bf(v[0]*scale); p[1] = f2bf(v[1]*scale);
      p[2] = f2bf(v[2]*scale); p[3] = f2bf(v[3]*scale);
      *(u16x4*)(row + (((sq4 + 4*j2)*8) ^ ssw)) = p;
    }
  } else {
    const int vg = tid >> 6, vc = tid & 63;
    const float* src = tv + ((size_t)(b*1024 + t*64))*256 + h*64 + vc;
#pragma unroll
    for (int kp = 0; kp < 2; ++kp)
#pragma unroll
      for (int tu = 0; tu < 2; ++tu) {
        const int y0 = 32*kp + 16*tu + 4*vg;
        u16x4 p;
#pragma unroll
        for (int j2 = 0; j2 < 4; ++j2)
          p[j2] = f2bf(src[(size_t)(y0 + j2)*256] * 4.8828125e-4f);
        *(u16x4*)&dst[((kp*4 + vg)*64 + vc)*8 + 4*tu] = p;
      }
  }
}

// ---------------- main: dbuf K/V via global_load_lds, 1 barrier/iter ----------------
__global__ __launch_bounds__(256)
void hstu_main(const unsigned short* __restrict__ Kb, const unsigned short* __restrict__ Qb,
               const unsigned short* __restrict__ Vb, const int* __restrict__ ncand,
               float* __restrict__ out)
{
  const int bid = (int)blockIdx.x;
  const int bh = bid & 31;             // same (b,h) -> same XCD
  const int jp = bid >> 5;
  // balance: co-resident pair (bid, bid+256) => (jp, jp+8); nkv sums ~19
  const int qtile = (jp == 0) ? 0 : (jp == 8) ? 1 : (jp < 8 ? jp + 1 : 24 - jp);
  const int b = bh >> 2, h = bh & 3;
  const int tid = (int)threadIdx.x;
  const int w = tid >> 6, l = tid & 63;
  const int rl = l & 15, g = l >> 4;
  const int T = 1024 - ncand[b];
  const int qbase = qtile << 6;

  __shared__ unsigned short Qlds[4096];
  __shared__ unsigned short Klds[2][4096];
  __shared__ unsigned short Vlds[2][4096];

  const char* kt  = (const char*)(Kb + (size_t)bh * 16 * 4096);
  const char* vtb = (const char*)(Vb + (size_t)bh * 16 * 4096);

  // stage Q (8 KB) via global_load_lds
  {
    const char* qs = (const char*)(Qb + ((size_t)bh*16 + qtile)*4096) + w*2048 + l*16;
    char* qd = (char*)Qlds + w*2048;
    gl_lds16(qs, qd);
    gl_lds16(qs + 1024, qd + 1024);
  }

  auto stage = [&](int buf, int kv) {
    const char* ks = kt + (size_t)kv*8192 + w*2048 + l*16;
    char* kd = (char*)Klds[buf] + w*2048;
    gl_lds16(ks, kd); gl_lds16(ks + 1024, kd + 1024);
    const char* vs = vtb + (size_t)kv*8192 + w*2048 + l*16;
    char* vd = (char*)Vlds[buf] + w*2048;
    gl_lds16(vs, vd); gl_lds16(vs + 1024, vd + 1024);
  };

  stage(0, 0);
  __syncthreads();

  // Q frags (B operand)
  s16x8 qf0, qf1;
  {
    const int qr = w*16 + rl;
    const char* base = (const char*)Qlds + qr*128;
    const int sw = (qr & 7) << 4;
    qf0 = *(const s16x8*)(base + ((g*16) ^ sw));
    qf1 = *(const s16x8*)(base + ((64 + g*16) ^ sw));
  }

  f32x4 zero = {0.f, 0.f, 0.f, 0.f};
  f32x4 oacc[4];
#pragma unroll
  for (int i = 0; i < 4; ++i) oacc[i] = zero;

  const int rq = qbase + w*16 + rl;
  const int nkv = (qtile == 0) ? 16 : (qtile + 1);

  for (int t = 0; t < nkv; ++t) {
    const int cur = t & 1;
    if (t + 1 < nkv) stage(cur ^ 1, t + 1);   // issue-early; hides under compute

    if (qtile != 0 || t == 0 || w == 0) {
      // QK^T swapped: S^T, A=K frag (row y), B=Q frag (col r)
      f32x4 sacc[4];
#pragma unroll
      for (int i = 0; i < 4; ++i) sacc[i] = zero;
      const char* kb = (const char*)Klds[cur];
#pragma unroll
      for (int t4 = 0; t4 < 4; ++t4) {
        const int kr = t4*16 + rl;
        const char* base = kb + kr*128;
        const int sw = (kr & 7) << 4;
        s16x8 kf0 = *(const s16x8*)(base + ((g*16) ^ sw));
        s16x8 kf1 = *(const s16x8*)(base + ((64 + g*16) ^ sw));
        sacc[t4] = __builtin_amdgcn_mfma_f32_16x16x32_bf16(kf0, qf0, sacc[t4], 0, 0, 0);
        sacc[t4] = __builtin_amdgcn_mfma_f32_16x16x32_bf16(kf1, qf1, sacc[t4], 0, 0, 0);
      }
      // silu + mask + pack P
      s16x8 pa0, pa1;
#pragma unroll
      for (int t4 = 0; t4 < 4; ++t4) {
#pragma unroll
        for (int r = 0; r < 4; ++r) {
          const int y = t*64 + t4*16 + 4*g + r;
          const float s = sacc[t4][r];
          const float sig = __builtin_amdgcn_rcpf(1.f + __expf(-s));
          const bool valid = (rq < 8) ? (y < T)
                           : ((y <= rq) && ((rq < T) || (y < T) || (y == rq)));
          const float a = valid ? s * sig : 0.f;
          const short bv = (short)f2bf(a);
          if (t4 < 2) pa0[(t4 & 1)*4 + r] = bv;
          else        pa1[(t4 & 1)*4 + r] = bv;
        }
      }
      // PV from permuted V image
      const unsigned short* vb = Vlds[cur];
#pragma unroll
      for (int vt = 0; vt < 4; ++vt) {
        const s16x8 vf0 = *(const s16x8*)&vb[((0*4 + g)*64 + vt*16 + rl)*8];
        oacc[vt] = __builtin_amdgcn_mfma_f32_16x16x32_bf16(pa0, vf0, oacc[vt], 0, 0, 0);
        const s16x8 vf1 = *(const s16x8*)&vb[((1*4 + g)*64 + vt*16 + rl)*8];
        oacc[vt] = __builtin_amdgcn_mfma_f32_16x16x32_bf16(pa1, vf1, oacc[vt], 0, 0, 0);
      }
    }
    __syncthreads();   // drains vmcnt -> next buffer ready; protects overwrite
  }

  float* dst = out + ((size_t)(b*1024 + qbase + w*16))*256 + h*64;
#pragma unroll
  for (int vt = 0; vt < 4; ++vt)
#pragma unroll
    for (int r = 0; r < 4; ++r)
      dst[(size_t)(4*g + r)*256 + vt*16 + rl] = oacc[vt][r];
}

extern "C" void kernel_launch(void* const* d_in, const int* in_sizes, int n_in,
                              void* d_out, int out_size, void* d_ws, size_t ws_size,
                              hipStream_t stream) {
  (void)in_sizes; (void)n_in; (void)out_size; (void)ws_size;
  const float* tq = (const float*)d_in[0];
  const float* tk = (const float*)d_in[1];
  const float* tv = (const float*)d_in[2];
  const int*   nc = (const int*)d_in[4];
  float* out = (float*)d_out;
  unsigned short* ws = (unsigned short*)d_ws;   // needs 12 MB

  hipLaunchKernelGGL(prep_all, dim3(1536), dim3(256), 0, stream, tq, tk, tv, ws);
  const unsigned short* Kb = ws;
  const unsigned short* Qb = ws + 2097152;
  const unsigned short* Vb = ws + 4194304;
  hipLaunchKernelGGL(hstu_main, dim3(512), dim3(256), 0, stream, Kb, Qb, Vb, nc, out);
}